// Round 7
// baseline (225.302 us; speedup 1.0000x reference)
//
#include <hip/hip_runtime.h>
#include <math.h>

// Problem constants
#define S 512
#define C 384
#define H 12
#define SCALAR_SCALE 0.25f   // 16^-0.5
#define NEG_LOGIT (-10000.0f)

// X layout per row (1152 cols): [qs 192 | ks 192 | vs 192 | qp 144 | kp 144 | vp 288]
#define XCOLS 1152
#define DQK 28   // fused logit dim: 16 scalar + 12 weighted point
#define DV 40    // fused value dim: 16 scalar + 24 global point

// ---------------------------------------------------------------------------
// Projection GEMM with fused weight gather (wcat eliminated):
// X[m, n] = single[m,:384] @ Wcat[:,n] + bcat[n], where Wcat/bcat are gathered
// on the fly from the 6 projection weights.  64x64 tiles, 256 thr, 4x4 micro.
// ---------------------------------------------------------------------------
__global__ __launch_bounds__(256)
void gemm_proj(const float* __restrict__ A,
               const float* __restrict__ Wq_s, const float* __restrict__ bq_s,
               const float* __restrict__ Wk_s, const float* __restrict__ bk_s,
               const float* __restrict__ Wv_s, const float* __restrict__ bv_s,
               const float* __restrict__ Wq_p, const float* __restrict__ bq_p,
               const float* __restrict__ Wk_p, const float* __restrict__ bk_p,
               const float* __restrict__ Wv_p, const float* __restrict__ bv_p,
               float* __restrict__ X)
{
    __shared__ float As[16][65];
    __shared__ float Bs[16][65];
    const int tid = threadIdx.x;
    const int m0 = blockIdx.y * 64;
    const int n0 = blockIdx.x * 64;
    const int ty = tid >> 4;
    const int tx = tid & 15;

    // per-thread gather source for column n = n0 + (tid&15)*4 (same col used
    // by both the B-loader role and the bias epilogue)
    const int n = n0 + tx * 4;
    const float* bsrc; const float* bbias; int ldbs, ncol;
    if      (n < 192) { bsrc = Wq_s; bbias = bq_s; ldbs = 192; ncol = n; }
    else if (n < 384) { bsrc = Wk_s; bbias = bk_s; ldbs = 192; ncol = n - 192; }
    else if (n < 576) { bsrc = Wv_s; bbias = bv_s; ldbs = 192; ncol = n - 384; }
    else if (n < 720) { bsrc = Wq_p; bbias = bq_p; ldbs = 144; ncol = n - 576; }
    else if (n < 864) { bsrc = Wk_p; bbias = bk_p; ldbs = 144; ncol = n - 720; }
    else              { bsrc = Wv_p; bbias = bv_p; ldbs = 288; ncol = n - 864; }

    float acc[4][4] = {};

    for (int k0 = 0; k0 < C; k0 += 16) {
        {
            int r = tid >> 2;
            int c = (tid & 3) * 4;
            const float4 v = *(const float4*)(A + (size_t)(m0 + r) * C + k0 + c);
            As[c + 0][r] = v.x; As[c + 1][r] = v.y;
            As[c + 2][r] = v.z; As[c + 3][r] = v.w;
        }
        {
            int r = tid >> 4;   // k within tile
            const float4 v = *(const float4*)(bsrc + (size_t)(k0 + r) * ldbs + ncol);
            int c = tx * 4;
            Bs[r][c + 0] = v.x; Bs[r][c + 1] = v.y;
            Bs[r][c + 2] = v.z; Bs[r][c + 3] = v.w;
        }
        __syncthreads();
        #pragma unroll
        for (int k = 0; k < 16; ++k) {
            float a[4], b[4];
            #pragma unroll
            for (int i = 0; i < 4; ++i) a[i] = As[k][ty * 4 + i];
            #pragma unroll
            for (int j = 0; j < 4; ++j) b[j] = Bs[k][tx * 4 + j];
            #pragma unroll
            for (int i = 0; i < 4; ++i)
                #pragma unroll
                for (int j = 0; j < 4; ++j)
                    acc[i][j] += a[i] * b[j];
        }
        __syncthreads();
    }

    const float4 bb = *(const float4*)(bbias + ncol);
    #pragma unroll
    for (int i = 0; i < 4; ++i) {
        int m = m0 + ty * 4 + i;
        float4 o = make_float4(acc[i][0] + bb.x, acc[i][1] + bb.y,
                               acc[i][2] + bb.z, acc[i][3] + bb.w);
        *(float4*)(X + (size_t)m * XCOLS + n) = o;
    }
}

// ---------------------------------------------------------------------------
// 32x32-tile GEMM for the output projection:
// out[m,n] = (combined[m,:576] @ Wo[:,n] + bo[n]) * rowMask[m]
// ---------------------------------------------------------------------------
__global__ __launch_bounds__(256)
void gemm_out(const float* __restrict__ A, int lda,
              const float* __restrict__ B, int ldb,
              const float* __restrict__ bias,
              float* __restrict__ Cc, int ldc, int K,
              const int* __restrict__ rowMask)
{
    __shared__ float As[16][33];
    __shared__ float Bs[16][33];
    const int tid = threadIdx.x;
    const int m0 = blockIdx.y * 32;
    const int n0 = blockIdx.x * 32;
    const int ty = tid >> 4;     // 0..15
    const int tx = tid & 15;     // 0..15

    float acc[2][2] = {};

    for (int k0 = 0; k0 < K; k0 += 16) {
        {
            int r = tid >> 3;            // 0..31
            int c = (tid & 7) * 2;       // 0..14
            const float2 v = *(const float2*)(A + (size_t)(m0 + r) * lda + k0 + c);
            As[c + 0][r] = v.x; As[c + 1][r] = v.y;
        }
        {
            int r = tid >> 4;            // 0..15
            int c = (tid & 15) * 2;      // 0..30
            const float2 v = *(const float2*)(B + (size_t)(k0 + r) * ldb + n0 + c);
            Bs[r][c + 0] = v.x; Bs[r][c + 1] = v.y;
        }
        __syncthreads();
        #pragma unroll
        for (int k = 0; k < 16; ++k) {
            float a0 = As[k][ty * 2], a1 = As[k][ty * 2 + 1];
            float b0 = Bs[k][tx * 2], b1 = Bs[k][tx * 2 + 1];
            acc[0][0] += a0 * b0; acc[0][1] += a0 * b1;
            acc[1][0] += a1 * b0; acc[1][1] += a1 * b1;
        }
        __syncthreads();
    }

    #pragma unroll
    for (int i = 0; i < 2; ++i) {
        int m = m0 + ty * 2 + i;
        float msk = rowMask[m] ? 1.0f : 0.0f;
        #pragma unroll
        for (int j = 0; j < 2; ++j) {
            int n = n0 + tx * 2 + j;
            Cc[(size_t)m * ldc + n] = (acc[i][j] + bias[n]) * msk;
        }
    }
}

// ---------------------------------------------------------------------------
// Build fused Q/K/V in d-major float4 layouts + key bias.
// ---------------------------------------------------------------------------
__global__ __launch_bounds__(256)
void ipa_points(const float* __restrict__ X,
                const float* __restrict__ rot,      // [S][3][3]
                const float* __restrict__ trans,    // [S][3]
                const float* __restrict__ pw,       // [H][4]
                float4* __restrict__ Q4, float4* __restrict__ K4,
                float4* __restrict__ V4, float* __restrict__ kb)
{
    int idx = blockIdx.x * 256 + threadIdx.x;   // 0..6143
    int h = idx >> 9;
    int s = idx & 511;

    float R[9], t[3];
    #pragma unroll
    for (int i = 0; i < 9; ++i) R[i] = rot[s * 9 + i];
    #pragma unroll
    for (int i = 0; i < 3; ++i) t[i] = trans[s * 3 + i];

    float spw[4];
    #pragma unroll
    for (int p = 0; p < 4; ++p)
        spw[p] = log1pf(__expf(pw[h * 4 + p]));

    const float4* xr4 = (const float4*)(X + (size_t)s * XCOLS);

    float qv[DQK], kv[DQK], vv[DV];
    #pragma unroll
    for (int g = 0; g < 4; ++g) {
        float4 a = xr4[h * 4 + g];               // qs
        qv[g * 4 + 0] = a.x * SCALAR_SCALE; qv[g * 4 + 1] = a.y * SCALAR_SCALE;
        qv[g * 4 + 2] = a.z * SCALAR_SCALE; qv[g * 4 + 3] = a.w * SCALAR_SCALE;
        float4 b = xr4[48 + h * 4 + g];          // ks
        kv[g * 4 + 0] = b.x; kv[g * 4 + 1] = b.y; kv[g * 4 + 2] = b.z; kv[g * 4 + 3] = b.w;
        float4 c = xr4[96 + h * 4 + g];          // vs
        vv[g * 4 + 0] = c.x; vv[g * 4 + 1] = c.y; vv[g * 4 + 2] = c.z; vv[g * 4 + 3] = c.w;
    }
    float qp[12], kp[12], vp[24];
    #pragma unroll
    for (int g = 0; g < 3; ++g) {
        float4 a = xr4[144 + h * 3 + g];
        qp[g * 4 + 0] = a.x; qp[g * 4 + 1] = a.y; qp[g * 4 + 2] = a.z; qp[g * 4 + 3] = a.w;
        float4 b = xr4[180 + h * 3 + g];
        kp[g * 4 + 0] = b.x; kp[g * 4 + 1] = b.y; kp[g * 4 + 2] = b.z; kp[g * 4 + 3] = b.w;
    }
    #pragma unroll
    for (int g = 0; g < 6; ++g) {
        float4 a = xr4[216 + h * 6 + g];
        vp[g * 4 + 0] = a.x; vp[g * 4 + 1] = a.y; vp[g * 4 + 2] = a.z; vp[g * 4 + 3] = a.w;
    }

    float knorm = 0.0f;
    #pragma unroll
    for (int p = 0; p < 4; ++p) {
        #pragma unroll
        for (int i = 0; i < 3; ++i) {
            float qg = R[i * 3] * qp[p * 3] + R[i * 3 + 1] * qp[p * 3 + 1] + R[i * 3 + 2] * qp[p * 3 + 2] + t[i];
            float kg = R[i * 3] * kp[p * 3] + R[i * 3 + 1] * kp[p * 3 + 1] + R[i * 3 + 2] * kp[p * 3 + 2] + t[i];
            qv[16 + p * 3 + i] = spw[p] * qg;
            kv[16 + p * 3 + i] = kg;
            knorm += spw[p] * kg * kg;
        }
    }
    kb[(size_t)h * S + s] = -0.5f * knorm;

    #pragma unroll
    for (int p = 0; p < 8; ++p) {
        #pragma unroll
        for (int i = 0; i < 3; ++i)
            vv[16 + p * 3 + i] = R[i * 3] * vp[p * 3] + R[i * 3 + 1] * vp[p * 3 + 1] + R[i * 3 + 2] * vp[p * 3 + 2] + t[i];
    }

    #pragma unroll
    for (int g = 0; g < 7; ++g)
        Q4[((size_t)h * 7 + g) * S + s] = make_float4(qv[g * 4], qv[g * 4 + 1], qv[g * 4 + 2], qv[g * 4 + 3]);
    #pragma unroll
    for (int g = 0; g < 7; ++g)
        K4[((size_t)h * 7 + g) * S + s] = make_float4(kv[g * 4], kv[g * 4 + 1], kv[g * 4 + 2], kv[g * 4 + 3]);
    #pragma unroll
    for (int g = 0; g < 10; ++g)
        V4[((size_t)h * 10 + g) * S + s] = make_float4(vv[g * 4], vv[g * 4 + 1], vv[g * 4 + 2], vv[g * 4 + 3]);
}

// ---------------------------------------------------------------------------
// Attention: block = (head, 4 query rows), 4 waves, wave = 1 row.
// K/V staged per 64-key tile in double-buffered LDS (shared by the 4 waves);
// issue-early/write-late staging hides HBM/L2 latency under compute.
// Online (flash) softmax -> single pass over keys.  Epilogue via LDS stage.
// ---------------------------------------------------------------------------
__global__ __launch_bounds__(256)
void ipa_attn(const float4* __restrict__ Q4, const float4* __restrict__ K4,
              const float4* __restrict__ V4, const float* __restrict__ kb,
              const int* __restrict__ valid,
              const float* __restrict__ rot, const float* __restrict__ trans,
              float* __restrict__ combined)
{
    __shared__ float4 Kl[2][448];   // [g*64 + j]
    __shared__ float4 Vl[2][640];
    __shared__ float4 sh[4][10];
    const int h = blockIdx.x;
    const int tid = threadIdx.x;
    const int wave = tid >> 6;
    const int lane = tid & 63;
    const int i = blockIdx.y * 4 + wave;

    // broadcast-load fused query (7 float4)
    float q[DQK];
    #pragma unroll
    for (int g = 0; g < 7; ++g) {
        float4 v = Q4[((size_t)h * 7 + g) * S + i];
        q[g * 4] = v.x; q[g * 4 + 1] = v.y; q[g * 4 + 2] = v.z; q[g * 4 + 3] = v.w;
    }
    // per-lane key bias + valid flag for this lane's key in each of 8 tiles
    float kbv[8]; int vld[8];
    #pragma unroll
    for (int t = 0; t < 8; ++t) {
        kbv[t] = kb[(size_t)h * S + t * 64 + lane];
        vld[t] = valid[t * 64 + lane];
    }

    // prologue: stage tile 0 into buffer 0
    Kl[0][tid] = K4[((size_t)h * 7 + (tid >> 6)) * S + (tid & 63)];
    if (tid < 192)
        Kl[0][tid + 256] = K4[((size_t)h * 7 + ((tid + 256) >> 6)) * S + ((tid + 256) & 63)];
    Vl[0][tid] = V4[((size_t)h * 10 + (tid >> 6)) * S + (tid & 63)];
    Vl[0][tid + 256] = V4[((size_t)h * 10 + ((tid + 256) >> 6)) * S + ((tid + 256) & 63)];
    if (tid < 128)
        Vl[0][tid + 512] = V4[((size_t)h * 10 + ((tid + 512) >> 6)) * S + ((tid + 512) & 63)];

    float4 acc[10];
    #pragma unroll
    for (int g = 0; g < 10; ++g) acc[g] = make_float4(0.f, 0.f, 0.f, 0.f);
    float m = -3.0e38f, sum = 0.0f;
    float4 rk0, rk1, rv0, rv1, rv2;

    #pragma unroll
    for (int t = 0; t < 8; ++t) {
        const int b = t & 1, nb = b ^ 1;
        if (t < 7) {   // issue next-tile global loads early (T14 split)
            const int t0 = (t + 1) * 64;
            rk0 = K4[((size_t)h * 7 + (tid >> 6)) * S + t0 + (tid & 63)];
            if (tid < 192)
                rk1 = K4[((size_t)h * 7 + ((tid + 256) >> 6)) * S + t0 + ((tid + 256) & 63)];
            rv0 = V4[((size_t)h * 10 + (tid >> 6)) * S + t0 + (tid & 63)];
            rv1 = V4[((size_t)h * 10 + ((tid + 256) >> 6)) * S + t0 + ((tid + 256) & 63)];
            if (tid < 128)
                rv2 = V4[((size_t)h * 10 + ((tid + 512) >> 6)) * S + t0 + ((tid + 512) & 63)];
        }
        __syncthreads();   // tile t's LDS writes visible

        // logit for this lane's key
        float dot = kbv[t];
        #pragma unroll
        for (int g = 0; g < 7; ++g) {
            float4 k = Kl[b][g * 64 + lane];
            dot += q[g * 4] * k.x + q[g * 4 + 1] * k.y + q[g * 4 + 2] * k.z + q[g * 4 + 3] * k.w;
        }
        float lg = vld[t] ? dot : NEG_LOGIT;
        // tile max across the wave
        float lm = lg;
        #pragma unroll
        for (int off = 32; off >= 1; off >>= 1)
            lm = fmaxf(lm, __shfl_xor(lm, off, 64));
        float mnew = fmaxf(m, lm);
        float sc = __expf(m - mnew);     // wave-uniform
        float p = __expf(lg - mnew);
        sum = sum * sc + p;
        #pragma unroll
        for (int g = 0; g < 10; ++g) {
            float4 v = Vl[b][g * 64 + lane];
            acc[g].x = acc[g].x * sc + p * v.x;
            acc[g].y = acc[g].y * sc + p * v.y;
            acc[g].z = acc[g].z * sc + p * v.z;
            acc[g].w = acc[g].w * sc + p * v.w;
        }
        m = mnew;

        __syncthreads();   // all waves done reading buffer nb's old tile
        if (t < 7) {       // write staged regs to LDS
            Kl[nb][tid] = rk0;
            if (tid < 192) Kl[nb][tid + 256] = rk1;
            Vl[nb][tid] = rv0;
            Vl[nb][tid + 256] = rv1;
            if (tid < 128) Vl[nb][tid + 512] = rv2;
        }
    }

    // reduce across lanes
    #pragma unroll
    for (int off = 32; off >= 1; off >>= 1)
        sum += __shfl_xor(sum, off, 64);
    #pragma unroll
    for (int g = 0; g < 10; ++g) {
        #pragma unroll
        for (int off = 32; off >= 1; off >>= 1) {
            acc[g].x += __shfl_xor(acc[g].x, off, 64);
            acc[g].y += __shfl_xor(acc[g].y, off, 64);
            acc[g].z += __shfl_xor(acc[g].z, off, 64);
            acc[g].w += __shfl_xor(acc[g].w, off, 64);
        }
    }
    const float inv = 1.0f / sum;

    if (lane == 0) {
        #pragma unroll
        for (int g = 0; g < 10; ++g) sh[wave][g] = acc[g];
    }
    const float* shf = (const float*)sh[wave];

    float* crow = combined + (size_t)i * 576;
    if (lane < 16)
        crow[h * 16 + lane] = shf[lane] * inv;

    if (lane < 8) {
        float R[9], t_[3];
        #pragma unroll
        for (int a = 0; a < 9; ++a) R[a] = rot[i * 9 + a];
        #pragma unroll
        for (int a = 0; a < 3; ++a) t_[a] = trans[i * 3 + a];
        int p = lane;
        float d0 = shf[16 + p * 3 + 0] * inv - t_[0];
        float d1 = shf[16 + p * 3 + 1] * inv - t_[1];
        float d2 = shf[16 + p * 3 + 2] * inv - t_[2];
        float pol0 = R[0] * d0 + R[3] * d1 + R[6] * d2;
        float pol1 = R[1] * d0 + R[4] * d1 + R[7] * d2;
        float pol2 = R[2] * d0 + R[5] * d1 + R[8] * d2;
        crow[192 + h * 24 + p * 3 + 0] = pol0;
        crow[192 + h * 24 + p * 3 + 1] = pol1;
        crow[192 + h * 24 + p * 3 + 2] = pol2;
        crow[480 + h * 8 + p] = sqrtf(pol0 * pol0 + pol1 * pol1 + pol2 * pol2);
    }
}

// ---------------------------------------------------------------------------
extern "C" void kernel_launch(void* const* d_in, const int* in_sizes, int n_in,
                              void* d_out, int out_size, void* d_ws, size_t ws_size,
                              hipStream_t stream)
{
    const float* single = (const float*)d_in[0];
    const float* rot    = (const float*)d_in[1];
    const float* trans  = (const float*)d_in[2];
    const float* Wq_s   = (const float*)d_in[3];
    const float* bq_s   = (const float*)d_in[4];
    const float* Wk_s   = (const float*)d_in[5];
    const float* bk_s   = (const float*)d_in[6];
    const float* Wv_s   = (const float*)d_in[7];
    const float* bv_s   = (const float*)d_in[8];
    const float* Wq_p   = (const float*)d_in[9];
    const float* bq_p   = (const float*)d_in[10];
    const float* Wk_p   = (const float*)d_in[11];
    const float* bk_p   = (const float*)d_in[12];
    const float* Wv_p   = (const float*)d_in[13];
    const float* bv_p   = (const float*)d_in[14];
    const float* pw     = (const float*)d_in[15];
    const float* Wo     = (const float*)d_in[16];
    const float* bo     = (const float*)d_in[17];
    const int*   valid  = (const int*)d_in[18];

    float* ws = (float*)d_ws;
    float* X        = ws;                                  // 512*1152
    float* Q4f      = X + (size_t)S * XCOLS;               // 12*7*512*4
    float* K4f      = Q4f + (size_t)H * 7 * S * 4;
    float* V4f      = K4f + (size_t)H * 7 * S * 4;         // 12*10*512*4
    float* kbb      = V4f + (size_t)H * 10 * S * 4;        // 12*512
    float* combined = kbb + (size_t)H * S;                 // 512*576

    dim3 blk(256);

    // 1. fused projection GEMM with on-the-fly weight gather (512x1152x384)
    gemm_proj<<<dim3(XCOLS / 64, S / 64), blk, 0, stream>>>(
        single, Wq_s, bq_s, Wk_s, bk_s, Wv_s, bv_s,
        Wq_p, bq_p, Wk_p, bk_p, Wv_p, bv_p, X);

    // 2. fused Q/K/V build (rotations applied, d-major float4 layout)
    ipa_points<<<dim3(S * H / 256), blk, 0, stream>>>(X, rot, trans, pw,
                                                      (float4*)Q4f, (float4*)K4f, (float4*)V4f, kbb);

    // 3. attention -> combined (LDS-staged flash)
    ipa_attn<<<dim3(H, S / 4), blk, 0, stream>>>((const float4*)Q4f, (const float4*)K4f,
                                                 (const float4*)V4f, kbb, valid, rot, trans, combined);

    // 4. output projection with query-row masking
    gemm_out<<<dim3(C / 32, S / 32), blk, 0, stream>>>(combined, 576, Wo, C, bo, (float*)d_out, C, 576, valid);
}

// Round 10
// 189.274 us; speedup vs baseline: 1.1903x; 1.1903x over previous
//
#include <hip/hip_runtime.h>
#include <math.h>

// Problem constants
#define S 512
#define C 384
#define H 12
#define SCALAR_SCALE 0.25f   // 16^-0.5
#define NEG_LOGIT (-10000.0f)

// X layout per row (1152 cols): [qs 192 | ks 192 | vs 192 | qp 144 | kp 144 | vp 288]
#define XCOLS 1152
#define DQK 28   // fused logit dim: 16 scalar + 12 weighted point
#define DV 40    // fused value dim: 16 scalar + 24 global point

// ---------------------------------------------------------------------------
// Projection GEMM with fused weight gather: X = single @ Wcat + bcat.
// 64x64 tiles, BK=48 (8 barrier iterations), 256 thr, 4x4 micro-tile.
// ---------------------------------------------------------------------------
__global__ __launch_bounds__(256)
void gemm_proj(const float* __restrict__ A,
               const float* __restrict__ Wq_s, const float* __restrict__ bq_s,
               const float* __restrict__ Wk_s, const float* __restrict__ bk_s,
               const float* __restrict__ Wv_s, const float* __restrict__ bv_s,
               const float* __restrict__ Wq_p, const float* __restrict__ bq_p,
               const float* __restrict__ Wk_p, const float* __restrict__ bk_p,
               const float* __restrict__ Wv_p, const float* __restrict__ bv_p,
               float* __restrict__ X)
{
    __shared__ float As[48][65];
    __shared__ float Bs[48][65];
    const int tid = threadIdx.x;
    const int m0 = blockIdx.y * 64;
    const int n0 = blockIdx.x * 64;
    const int ty = tid >> 4;
    const int tx = tid & 15;

    // per-thread gather source for column n = n0 + tx*4
    const int n = n0 + tx * 4;
    const float* bsrc; const float* bbias; int ldbs, ncol;
    if      (n < 192) { bsrc = Wq_s; bbias = bq_s; ldbs = 192; ncol = n; }
    else if (n < 384) { bsrc = Wk_s; bbias = bk_s; ldbs = 192; ncol = n - 192; }
    else if (n < 576) { bsrc = Wv_s; bbias = bv_s; ldbs = 192; ncol = n - 384; }
    else if (n < 720) { bsrc = Wq_p; bbias = bq_p; ldbs = 144; ncol = n - 576; }
    else if (n < 864) { bsrc = Wk_p; bbias = bk_p; ldbs = 144; ncol = n - 720; }
    else              { bsrc = Wv_p; bbias = bv_p; ldbs = 288; ncol = n - 864; }

    float acc[4][4] = {};

    for (int k0 = 0; k0 < C; k0 += 48) {
        {   // A tile 64 rows x 48 k, stored transposed As[k][m]; 3 float4/thread
            int r = tid >> 2;
            int cbase = (tid & 3) * 4;
            #pragma unroll
            for (int cc = 0; cc < 3; ++cc) {
                int c = cbase + cc * 16;
                const float4 v = *(const float4*)(A + (size_t)(m0 + r) * C + k0 + c);
                As[c + 0][r] = v.x; As[c + 1][r] = v.y;
                As[c + 2][r] = v.z; As[c + 3][r] = v.w;
            }
        }
        {   // B tile 48 k x 64 cols, gathered; 3 float4/thread (rows r, r+16, r+32)
            int r = tid >> 4;
            int c = tx * 4;
            #pragma unroll
            for (int rr = 0; rr < 3; ++rr) {
                const float4 v = *(const float4*)(bsrc + (size_t)(k0 + r + rr * 16) * ldbs + ncol);
                Bs[r + rr * 16][c + 0] = v.x; Bs[r + rr * 16][c + 1] = v.y;
                Bs[r + rr * 16][c + 2] = v.z; Bs[r + rr * 16][c + 3] = v.w;
            }
        }
        __syncthreads();
        #pragma unroll
        for (int k = 0; k < 48; ++k) {
            float a[4], b[4];
            #pragma unroll
            for (int i = 0; i < 4; ++i) a[i] = As[k][ty * 4 + i];
            #pragma unroll
            for (int j = 0; j < 4; ++j) b[j] = Bs[k][tx * 4 + j];
            #pragma unroll
            for (int i = 0; i < 4; ++i)
                #pragma unroll
                for (int j = 0; j < 4; ++j)
                    acc[i][j] += a[i] * b[j];
        }
        __syncthreads();
    }

    const float4 bb = *(const float4*)(bbias + ncol);
    #pragma unroll
    for (int i = 0; i < 4; ++i) {
        int m = m0 + ty * 4 + i;
        float4 o = make_float4(acc[i][0] + bb.x, acc[i][1] + bb.y,
                               acc[i][2] + bb.z, acc[i][3] + bb.w);
        *(float4*)(X + (size_t)m * XCOLS + n) = o;
    }
}

// ---------------------------------------------------------------------------
// Output projection, 32x32 tiles, BK=32 (18 barrier iterations):
// out[m,n] = (combined[m,:576] @ Wo[:,n] + bo[n]) * rowMask[m]
// ---------------------------------------------------------------------------
__global__ __launch_bounds__(256)
void gemm_out(const float* __restrict__ A, int lda,
              const float* __restrict__ B, int ldb,
              const float* __restrict__ bias,
              float* __restrict__ Cc, int ldc, int K,
              const int* __restrict__ rowMask)
{
    __shared__ float As[32][33];
    __shared__ float Bs[32][33];
    const int tid = threadIdx.x;
    const int m0 = blockIdx.y * 32;
    const int n0 = blockIdx.x * 32;
    const int ty = tid >> 4;     // 0..15
    const int tx = tid & 15;     // 0..15

    float acc[2][2] = {};

    for (int k0 = 0; k0 < K; k0 += 32) {
        {   // A tile 32 rows x 32 k, transposed As[k][m]; 1 float4/thread
            int r = tid >> 3;            // 0..31
            int c = (tid & 7) * 4;       // 0..28
            const float4 v = *(const float4*)(A + (size_t)(m0 + r) * lda + k0 + c);
            As[c + 0][r] = v.x; As[c + 1][r] = v.y;
            As[c + 2][r] = v.z; As[c + 3][r] = v.w;
        }
        {   // B tile 32 k x 32 cols; 1 float4/thread
            int r = tid >> 3;            // 0..31
            int c = (tid & 7) * 4;       // 0..28
            const float4 v = *(const float4*)(B + (size_t)(k0 + r) * ldb + n0 + c);
            Bs[r][c + 0] = v.x; Bs[r][c + 1] = v.y;
            Bs[r][c + 2] = v.z; Bs[r][c + 3] = v.w;
        }
        __syncthreads();
        #pragma unroll
        for (int k = 0; k < 32; ++k) {
            float a0 = As[k][ty * 2], a1 = As[k][ty * 2 + 1];
            float b0 = Bs[k][tx * 2], b1 = Bs[k][tx * 2 + 1];
            acc[0][0] += a0 * b0; acc[0][1] += a0 * b1;
            acc[1][0] += a1 * b0; acc[1][1] += a1 * b1;
        }
        __syncthreads();
    }

    #pragma unroll
    for (int i = 0; i < 2; ++i) {
        int m = m0 + ty * 2 + i;
        float msk = rowMask[m] ? 1.0f : 0.0f;
        #pragma unroll
        for (int j = 0; j < 2; ++j) {
            int n = n0 + tx * 2 + j;
            Cc[(size_t)m * ldc + n] = (acc[i][j] + bias[n]) * msk;
        }
    }
}

// ---------------------------------------------------------------------------
// Build fused Q/K/V in d-major float4 layouts + key bias.
// ---------------------------------------------------------------------------
__global__ __launch_bounds__(256)
void ipa_points(const float* __restrict__ X,
                const float* __restrict__ rot,      // [S][3][3]
                const float* __restrict__ trans,    // [S][3]
                const float* __restrict__ pw,       // [H][4]
                float4* __restrict__ Q4, float4* __restrict__ K4,
                float4* __restrict__ V4, float* __restrict__ kb)
{
    int idx = blockIdx.x * 256 + threadIdx.x;   // 0..6143
    int h = idx >> 9;
    int s = idx & 511;

    float R[9], t[3];
    #pragma unroll
    for (int i = 0; i < 9; ++i) R[i] = rot[s * 9 + i];
    #pragma unroll
    for (int i = 0; i < 3; ++i) t[i] = trans[s * 3 + i];

    float spw[4];
    #pragma unroll
    for (int p = 0; p < 4; ++p)
        spw[p] = log1pf(__expf(pw[h * 4 + p]));

    const float4* xr4 = (const float4*)(X + (size_t)s * XCOLS);

    float qv[DQK], kv[DQK], vv[DV];
    #pragma unroll
    for (int g = 0; g < 4; ++g) {
        float4 a = xr4[h * 4 + g];               // qs
        qv[g * 4 + 0] = a.x * SCALAR_SCALE; qv[g * 4 + 1] = a.y * SCALAR_SCALE;
        qv[g * 4 + 2] = a.z * SCALAR_SCALE; qv[g * 4 + 3] = a.w * SCALAR_SCALE;
        float4 b = xr4[48 + h * 4 + g];          // ks
        kv[g * 4 + 0] = b.x; kv[g * 4 + 1] = b.y; kv[g * 4 + 2] = b.z; kv[g * 4 + 3] = b.w;
        float4 c = xr4[96 + h * 4 + g];          // vs
        vv[g * 4 + 0] = c.x; vv[g * 4 + 1] = c.y; vv[g * 4 + 2] = c.z; vv[g * 4 + 3] = c.w;
    }
    float qp[12], kp[12], vp[24];
    #pragma unroll
    for (int g = 0; g < 3; ++g) {
        float4 a = xr4[144 + h * 3 + g];
        qp[g * 4 + 0] = a.x; qp[g * 4 + 1] = a.y; qp[g * 4 + 2] = a.z; qp[g * 4 + 3] = a.w;
        float4 b = xr4[180 + h * 3 + g];
        kp[g * 4 + 0] = b.x; kp[g * 4 + 1] = b.y; kp[g * 4 + 2] = b.z; kp[g * 4 + 3] = b.w;
    }
    #pragma unroll
    for (int g = 0; g < 6; ++g) {
        float4 a = xr4[216 + h * 6 + g];
        vp[g * 4 + 0] = a.x; vp[g * 4 + 1] = a.y; vp[g * 4 + 2] = a.z; vp[g * 4 + 3] = a.w;
    }

    float knorm = 0.0f;
    #pragma unroll
    for (int p = 0; p < 4; ++p) {
        #pragma unroll
        for (int i = 0; i < 3; ++i) {
            float qg = R[i * 3] * qp[p * 3] + R[i * 3 + 1] * qp[p * 3 + 1] + R[i * 3 + 2] * qp[p * 3 + 2] + t[i];
            float kg = R[i * 3] * kp[p * 3] + R[i * 3 + 1] * kp[p * 3 + 1] + R[i * 3 + 2] * kp[p * 3 + 2] + t[i];
            qv[16 + p * 3 + i] = spw[p] * qg;
            kv[16 + p * 3 + i] = kg;
            knorm += spw[p] * kg * kg;
        }
    }
    kb[(size_t)h * S + s] = -0.5f * knorm;

    #pragma unroll
    for (int p = 0; p < 8; ++p) {
        #pragma unroll
        for (int i = 0; i < 3; ++i)
            vv[16 + p * 3 + i] = R[i * 3] * vp[p * 3] + R[i * 3 + 1] * vp[p * 3 + 1] + R[i * 3 + 2] * vp[p * 3 + 2] + t[i];
    }

    #pragma unroll
    for (int g = 0; g < 7; ++g)
        Q4[((size_t)h * 7 + g) * S + s] = make_float4(qv[g * 4], qv[g * 4 + 1], qv[g * 4 + 2], qv[g * 4 + 3]);
    #pragma unroll
    for (int g = 0; g < 7; ++g)
        K4[((size_t)h * 7 + g) * S + s] = make_float4(kv[g * 4], kv[g * 4 + 1], kv[g * 4 + 2], kv[g * 4 + 3]);
    #pragma unroll
    for (int g = 0; g < 10; ++g)
        V4[((size_t)h * 10 + g) * S + s] = make_float4(vv[g * 4], vv[g * 4 + 1], vv[g * 4 + 2], vv[g * 4 + 3]);
}

// ---------------------------------------------------------------------------
// Attention (measured-good R6 version): one wave per (h, i); direct coalesced
// float4 loads from L2-resident d-major K/V; two-pass softmax in-register;
// butterfly reduces; LDS stage only for the epilogue's dynamic indexing.
// ---------------------------------------------------------------------------
__global__ __launch_bounds__(256)
void ipa_attn(const float4* __restrict__ Q4, const float4* __restrict__ K4,
              const float4* __restrict__ V4, const float* __restrict__ kb,
              const int* __restrict__ valid,
              const float* __restrict__ rot, const float* __restrict__ trans,
              float* __restrict__ combined)
{
    __shared__ float4 sh[4][10];
    const int h = blockIdx.x;
    const int wave = threadIdx.x >> 6;
    const int lane = threadIdx.x & 63;
    const int i = blockIdx.y * 4 + wave;

    // broadcast-load fused query (7 float4)
    float q[DQK];
    #pragma unroll
    for (int g = 0; g < 7; ++g) {
        float4 v = Q4[((size_t)h * 7 + g) * S + i];
        q[g * 4] = v.x; q[g * 4 + 1] = v.y; q[g * 4 + 2] = v.z; q[g * 4 + 3] = v.w;
    }

    const float* kbh = kb + (size_t)h * S;

    float logit[8];
    float mx = -3.0e38f;
    #pragma unroll
    for (int t = 0; t < 8; ++t) {
        int j = t * 64 + lane;
        float dot = kbh[j];
        #pragma unroll
        for (int g = 0; g < 7; ++g) {
            float4 k = K4[((size_t)h * 7 + g) * S + j];
            dot += q[g * 4] * k.x + q[g * 4 + 1] * k.y + q[g * 4 + 2] * k.z + q[g * 4 + 3] * k.w;
        }
        logit[t] = valid[j] ? dot : NEG_LOGIT;
        mx = fmaxf(mx, logit[t]);
    }
    #pragma unroll
    for (int off = 32; off >= 1; off >>= 1)
        mx = fmaxf(mx, __shfl_xor(mx, off, 64));

    float sum = 0.0f;
    #pragma unroll
    for (int t = 0; t < 8; ++t) {
        logit[t] = __expf(logit[t] - mx);
        sum += logit[t];
    }
    #pragma unroll
    for (int off = 32; off >= 1; off >>= 1)
        sum += __shfl_xor(sum, off, 64);
    const float inv = 1.0f / sum;

    // PV accumulate (unnormalized)
    float4 acc[10];
    #pragma unroll
    for (int g = 0; g < 10; ++g) acc[g] = make_float4(0.f, 0.f, 0.f, 0.f);
    #pragma unroll
    for (int t = 0; t < 8; ++t) {
        int j = t * 64 + lane;
        float p = logit[t];
        #pragma unroll
        for (int g = 0; g < 10; ++g) {
            float4 v = V4[((size_t)h * 10 + g) * S + j];
            acc[g].x += p * v.x; acc[g].y += p * v.y;
            acc[g].z += p * v.z; acc[g].w += p * v.w;
        }
    }
    #pragma unroll
    for (int g = 0; g < 10; ++g) {
        #pragma unroll
        for (int off = 32; off >= 1; off >>= 1) {
            acc[g].x += __shfl_xor(acc[g].x, off, 64);
            acc[g].y += __shfl_xor(acc[g].y, off, 64);
            acc[g].z += __shfl_xor(acc[g].z, off, 64);
            acc[g].w += __shfl_xor(acc[g].w, off, 64);
        }
    }

    // stage to LDS with static indices; read back with dynamic (LDS ok)
    if (lane == 0) {
        #pragma unroll
        for (int g = 0; g < 10; ++g) sh[wave][g] = acc[g];
    }
    const float* shf = (const float*)sh[wave];

    float* crow = combined + (size_t)i * 576;
    if (lane < 16)
        crow[h * 16 + lane] = shf[lane] * inv;

    if (lane < 8) {
        float R[9], t_[3];
        #pragma unroll
        for (int a = 0; a < 9; ++a) R[a] = rot[i * 9 + a];
        #pragma unroll
        for (int a = 0; a < 3; ++a) t_[a] = trans[i * 3 + a];
        int p = lane;
        float d0 = shf[16 + p * 3 + 0] * inv - t_[0];
        float d1 = shf[16 + p * 3 + 1] * inv - t_[1];
        float d2 = shf[16 + p * 3 + 2] * inv - t_[2];
        float pol0 = R[0] * d0 + R[3] * d1 + R[6] * d2;
        float pol1 = R[1] * d0 + R[4] * d1 + R[7] * d2;
        float pol2 = R[2] * d0 + R[5] * d1 + R[8] * d2;
        crow[192 + h * 24 + p * 3 + 0] = pol0;
        crow[192 + h * 24 + p * 3 + 1] = pol1;
        crow[192 + h * 24 + p * 3 + 2] = pol2;
        crow[480 + h * 8 + p] = sqrtf(pol0 * pol0 + pol1 * pol1 + pol2 * pol2);
    }
}

// ---------------------------------------------------------------------------
extern "C" void kernel_launch(void* const* d_in, const int* in_sizes, int n_in,
                              void* d_out, int out_size, void* d_ws, size_t ws_size,
                              hipStream_t stream)
{
    const float* single = (const float*)d_in[0];
    const float* rot    = (const float*)d_in[1];
    const float* trans  = (const float*)d_in[2];
    const float* Wq_s   = (const float*)d_in[3];
    const float* bq_s   = (const float*)d_in[4];
    const float* Wk_s   = (const float*)d_in[5];
    const float* bk_s   = (const float*)d_in[6];
    const float* Wv_s   = (const float*)d_in[7];
    const float* bv_s   = (const float*)d_in[8];
    const float* Wq_p   = (const float*)d_in[9];
    const float* bq_p   = (const float*)d_in[10];
    const float* Wk_p   = (const float*)d_in[11];
    const float* bk_p   = (const float*)d_in[12];
    const float* Wv_p   = (const float*)d_in[13];
    const float* bv_p   = (const float*)d_in[14];
    const float* pw     = (const float*)d_in[15];
    const float* Wo     = (const float*)d_in[16];
    const float* bo     = (const float*)d_in[17];
    const int*   valid  = (const int*)d_in[18];

    float* ws = (float*)d_ws;
    float* X        = ws;                                  // 512*1152
    float* Q4f      = X + (size_t)S * XCOLS;               // 12*7*512*4
    float* K4f      = Q4f + (size_t)H * 7 * S * 4;
    float* V4f      = K4f + (size_t)H * 7 * S * 4;         // 12*10*512*4
    float* kbb      = V4f + (size_t)H * 10 * S * 4;        // 12*512
    float* combined = kbb + (size_t)H * S;                 // 512*576

    dim3 blk(256);

    // 1. fused projection GEMM with on-the-fly weight gather (512x1152x384)
    gemm_proj<<<dim3(XCOLS / 64, S / 64), blk, 0, stream>>>(
        single, Wq_s, bq_s, Wk_s, bk_s, Wv_s, bv_s,
        Wq_p, bq_p, Wk_p, bk_p, Wv_p, bv_p, X);

    // 2. fused Q/K/V build (rotations applied, d-major float4 layout)
    ipa_points<<<dim3(S * H / 256), blk, 0, stream>>>(X, rot, trans, pw,
                                                      (float4*)Q4f, (float4*)K4f, (float4*)V4f, kbb);

    // 3. attention -> combined (direct-load two-pass, measured-good)
    ipa_attn<<<dim3(H, S / 4), blk, 0, stream>>>((const float4*)Q4f, (const float4*)K4f,
                                                 (const float4*)V4f, kbb, valid, rot, trans, combined);

    // 4. output projection with query-row masking
    gemm_out<<<dim3(C / 32, S / 32), blk, 0, stream>>>(combined, 576, Wo, C, bo, (float*)d_out, C, 576, valid);
}

// Round 12
// 189.063 us; speedup vs baseline: 1.1917x; 1.0011x over previous
//
#include <hip/hip_runtime.h>
#include <math.h>

// Problem constants
#define S 512
#define C 384
#define H 12
#define SCALAR_SCALE 0.25f   // 16^-0.5
#define NEG_LOGIT (-10000.0f)

// X layout per row (1152 cols): [qs 192 | ks 192 | vs 192 | qp 144 | kp 144 | vp 288]
#define XCOLS 1152
#define DQK 28   // fused logit dim: 16 scalar + 12 weighted point
#define DV 40    // fused value dim: 16 scalar + 24 global point

// ---------------------------------------------------------------------------
// Projection GEMM, split-K x2 with fused weight gather:
//   slice z covers k in [z*192, z*192+192), 4 iterations of BK=48.
//   slice 0 writes acc+bias to X0, slice 1 writes acc to X1 (no atomics);
//   ipa_points sums X0+X1.  Register prefetch hides tile loads under compute.
// ---------------------------------------------------------------------------
__global__ __launch_bounds__(256)
void gemm_proj(const float* __restrict__ A,
               const float* __restrict__ Wq_s, const float* __restrict__ bq_s,
               const float* __restrict__ Wk_s, const float* __restrict__ bk_s,
               const float* __restrict__ Wv_s, const float* __restrict__ bv_s,
               const float* __restrict__ Wq_p, const float* __restrict__ bq_p,
               const float* __restrict__ Wk_p, const float* __restrict__ bk_p,
               const float* __restrict__ Wv_p, const float* __restrict__ bv_p,
               float* __restrict__ X0)
{
    __shared__ float As[48][65];
    __shared__ float Bs[48][65];
    const int tid = threadIdx.x;
    const int m0 = blockIdx.y * 64;
    const int n0 = blockIdx.x * 64;
    const int z  = blockIdx.z;           // K slice
    const int ty = tid >> 4;
    const int tx = tid & 15;

    // per-thread gather source for column n = n0 + tx*4
    const int n = n0 + tx * 4;
    const float* bsrc; const float* bbias; int ldbs, ncol;
    if      (n < 192) { bsrc = Wq_s; bbias = bq_s; ldbs = 192; ncol = n; }
    else if (n < 384) { bsrc = Wk_s; bbias = bk_s; ldbs = 192; ncol = n - 192; }
    else if (n < 576) { bsrc = Wv_s; bbias = bv_s; ldbs = 192; ncol = n - 384; }
    else if (n < 720) { bsrc = Wq_p; bbias = bq_p; ldbs = 144; ncol = n - 576; }
    else if (n < 864) { bsrc = Wk_p; bbias = bk_p; ldbs = 144; ncol = n - 720; }
    else              { bsrc = Wv_p; bbias = bv_p; ldbs = 288; ncol = n - 864; }

    float* Xp = X0 + (size_t)z * S * XCOLS;

    const int ar  = tid >> 2;            // A row 0..63
    const int acb = (tid & 3) * 4;       // A col base 0,4,8,12 (stride 16 below)
    const int br  = tid >> 4;            // B row 0..15 (stride 16 below)

    // preload first tile (k0 = z*192) into registers
    float4 rA[3], rB[3];
    {
        const int k0 = z * 192;
        #pragma unroll
        for (int cc = 0; cc < 3; ++cc)
            rA[cc] = *(const float4*)(A + (size_t)(m0 + ar) * C + k0 + acb + cc * 16);
        #pragma unroll
        for (int rr = 0; rr < 3; ++rr)
            rB[rr] = *(const float4*)(bsrc + (size_t)(k0 + br + rr * 16) * ldbs + ncol);
    }

    float acc[4][4] = {};

    #pragma unroll
    for (int it = 0; it < 4; ++it) {
        // staged regs -> LDS
        #pragma unroll
        for (int cc = 0; cc < 3; ++cc) {
            int c = acb + cc * 16;
            As[c + 0][ar] = rA[cc].x; As[c + 1][ar] = rA[cc].y;
            As[c + 2][ar] = rA[cc].z; As[c + 3][ar] = rA[cc].w;
        }
        #pragma unroll
        for (int rr = 0; rr < 3; ++rr) {
            int c = tx * 4;
            Bs[br + rr * 16][c + 0] = rB[rr].x; Bs[br + rr * 16][c + 1] = rB[rr].y;
            Bs[br + rr * 16][c + 2] = rB[rr].z; Bs[br + rr * 16][c + 3] = rB[rr].w;
        }
        __syncthreads();

        // issue next tile's loads early; they complete under the compute below
        if (it < 3) {
            const int kn = z * 192 + (it + 1) * 48;
            #pragma unroll
            for (int cc = 0; cc < 3; ++cc)
                rA[cc] = *(const float4*)(A + (size_t)(m0 + ar) * C + kn + acb + cc * 16);
            #pragma unroll
            for (int rr = 0; rr < 3; ++rr)
                rB[rr] = *(const float4*)(bsrc + (size_t)(kn + br + rr * 16) * ldbs + ncol);
        }

        #pragma unroll
        for (int k = 0; k < 48; ++k) {
            float a[4], b[4];
            #pragma unroll
            for (int i = 0; i < 4; ++i) a[i] = As[k][ty * 4 + i];
            #pragma unroll
            for (int j = 0; j < 4; ++j) b[j] = Bs[k][tx * 4 + j];
            #pragma unroll
            for (int i = 0; i < 4; ++i)
                #pragma unroll
                for (int j = 0; j < 4; ++j)
                    acc[i][j] += a[i] * b[j];
        }
        __syncthreads();
    }

    if (z == 0) {
        const float4 bb = *(const float4*)(bbias + ncol);
        #pragma unroll
        for (int i = 0; i < 4; ++i) {
            int m = m0 + ty * 4 + i;
            *(float4*)(Xp + (size_t)m * XCOLS + n) =
                make_float4(acc[i][0] + bb.x, acc[i][1] + bb.y,
                            acc[i][2] + bb.z, acc[i][3] + bb.w);
        }
    } else {
        #pragma unroll
        for (int i = 0; i < 4; ++i) {
            int m = m0 + ty * 4 + i;
            *(float4*)(Xp + (size_t)m * XCOLS + n) =
                make_float4(acc[i][0], acc[i][1], acc[i][2], acc[i][3]);
        }
    }
}

// ---------------------------------------------------------------------------
// Output projection, 32x32 tiles, BK=48 (12 barrier iterations):
// out[m,n] = (combined[m,:576] @ Wo[:,n] + bo[n]) * rowMask[m]
// ---------------------------------------------------------------------------
__global__ __launch_bounds__(256)
void gemm_out(const float* __restrict__ A, int lda,
              const float* __restrict__ B, int ldb,
              const float* __restrict__ bias,
              float* __restrict__ Cc, int ldc, int K,
              const int* __restrict__ rowMask)
{
    __shared__ float As[48][33];
    __shared__ float Bs[48][33];
    const int tid = threadIdx.x;
    const int m0 = blockIdx.y * 32;
    const int n0 = blockIdx.x * 32;
    const int ty = tid >> 4;     // 0..15
    const int tx = tid & 15;     // 0..15

    float acc[2][2] = {};

    for (int k0 = 0; k0 < K; k0 += 48) {
        // A tile: 32 rows x 48 k -> 384 float4, transposed As[k][m]
        for (int idx = tid; idx < 384; idx += 256) {
            int r  = idx / 12;           // row 0..31
            int c4 = idx - r * 12;       // f4 index 0..11
            int c  = c4 * 4;
            const float4 v = *(const float4*)(A + (size_t)(m0 + r) * lda + k0 + c);
            As[c + 0][r] = v.x; As[c + 1][r] = v.y;
            As[c + 2][r] = v.z; As[c + 3][r] = v.w;
        }
        // B tile: 48 k x 32 cols -> 384 float4
        for (int idx = tid; idx < 384; idx += 256) {
            int r  = idx >> 3;           // k row 0..47
            int c  = (idx & 7) * 4;      // col 0..28
            const float4 v = *(const float4*)(B + (size_t)(k0 + r) * ldb + n0 + c);
            Bs[r][c + 0] = v.x; Bs[r][c + 1] = v.y;
            Bs[r][c + 2] = v.z; Bs[r][c + 3] = v.w;
        }
        __syncthreads();
        #pragma unroll
        for (int k = 0; k < 48; ++k) {
            float a0 = As[k][ty * 2], a1 = As[k][ty * 2 + 1];
            float b0 = Bs[k][tx * 2], b1 = Bs[k][tx * 2 + 1];
            acc[0][0] += a0 * b0; acc[0][1] += a0 * b1;
            acc[1][0] += a1 * b0; acc[1][1] += a1 * b1;
        }
        __syncthreads();
    }

    #pragma unroll
    for (int i = 0; i < 2; ++i) {
        int m = m0 + ty * 2 + i;
        float msk = rowMask[m] ? 1.0f : 0.0f;
        #pragma unroll
        for (int j = 0; j < 2; ++j) {
            int n = n0 + tx * 2 + j;
            Cc[(size_t)m * ldc + n] = (acc[i][j] + bias[n]) * msk;
        }
    }
}

// ---------------------------------------------------------------------------
// Build fused Q/K/V in d-major float4 layouts + key bias.  Input is the
// split-K pair X0/X1 (summed at load).
// ---------------------------------------------------------------------------
__device__ __forceinline__ float4 sum2(const float4* a, const float4* b, int i)
{
    float4 x = a[i], y = b[i];
    return make_float4(x.x + y.x, x.y + y.y, x.z + y.z, x.w + y.w);
}

__global__ __launch_bounds__(256)
void ipa_points(const float* __restrict__ X0,
                const float* __restrict__ rot,      // [S][3][3]
                const float* __restrict__ trans,    // [S][3]
                const float* __restrict__ pw,       // [H][4]
                float4* __restrict__ Q4, float4* __restrict__ K4,
                float4* __restrict__ V4, float* __restrict__ kb)
{
    int idx = blockIdx.x * 256 + threadIdx.x;   // 0..6143
    int h = idx >> 9;
    int s = idx & 511;

    float R[9], t[3];
    #pragma unroll
    for (int i = 0; i < 9; ++i) R[i] = rot[s * 9 + i];
    #pragma unroll
    for (int i = 0; i < 3; ++i) t[i] = trans[s * 3 + i];

    float spw[4];
    #pragma unroll
    for (int p = 0; p < 4; ++p)
        spw[p] = log1pf(__expf(pw[h * 4 + p]));

    const float4* xr0 = (const float4*)(X0 + (size_t)s * XCOLS);
    const float4* xr1 = (const float4*)(X0 + (size_t)S * XCOLS + (size_t)s * XCOLS);

    float qv[DQK], kv[DQK], vv[DV];
    #pragma unroll
    for (int g = 0; g < 4; ++g) {
        float4 a = sum2(xr0, xr1, h * 4 + g);          // qs
        qv[g * 4 + 0] = a.x * SCALAR_SCALE; qv[g * 4 + 1] = a.y * SCALAR_SCALE;
        qv[g * 4 + 2] = a.z * SCALAR_SCALE; qv[g * 4 + 3] = a.w * SCALAR_SCALE;
        float4 b = sum2(xr0, xr1, 48 + h * 4 + g);     // ks
        kv[g * 4 + 0] = b.x; kv[g * 4 + 1] = b.y; kv[g * 4 + 2] = b.z; kv[g * 4 + 3] = b.w;
        float4 c = sum2(xr0, xr1, 96 + h * 4 + g);     // vs
        vv[g * 4 + 0] = c.x; vv[g * 4 + 1] = c.y; vv[g * 4 + 2] = c.z; vv[g * 4 + 3] = c.w;
    }
    float qp[12], kp[12], vp[24];
    #pragma unroll
    for (int g = 0; g < 3; ++g) {
        float4 a = sum2(xr0, xr1, 144 + h * 3 + g);
        qp[g * 4 + 0] = a.x; qp[g * 4 + 1] = a.y; qp[g * 4 + 2] = a.z; qp[g * 4 + 3] = a.w;
        float4 b = sum2(xr0, xr1, 180 + h * 3 + g);
        kp[g * 4 + 0] = b.x; kp[g * 4 + 1] = b.y; kp[g * 4 + 2] = b.z; kp[g * 4 + 3] = b.w;
    }
    #pragma unroll
    for (int g = 0; g < 6; ++g) {
        float4 a = sum2(xr0, xr1, 216 + h * 6 + g);
        vp[g * 4 + 0] = a.x; vp[g * 4 + 1] = a.y; vp[g * 4 + 2] = a.z; vp[g * 4 + 3] = a.w;
    }

    float knorm = 0.0f;
    #pragma unroll
    for (int p = 0; p < 4; ++p) {
        #pragma unroll
        for (int i = 0; i < 3; ++i) {
            float qg = R[i * 3] * qp[p * 3] + R[i * 3 + 1] * qp[p * 3 + 1] + R[i * 3 + 2] * qp[p * 3 + 2] + t[i];
            float kg = R[i * 3] * kp[p * 3] + R[i * 3 + 1] * kp[p * 3 + 1] + R[i * 3 + 2] * kp[p * 3 + 2] + t[i];
            qv[16 + p * 3 + i] = spw[p] * qg;
            kv[16 + p * 3 + i] = kg;
            knorm += spw[p] * kg * kg;
        }
    }
    kb[(size_t)h * S + s] = -0.5f * knorm;

    #pragma unroll
    for (int p = 0; p < 8; ++p) {
        #pragma unroll
        for (int i = 0; i < 3; ++i)
            vv[16 + p * 3 + i] = R[i * 3] * vp[p * 3] + R[i * 3 + 1] * vp[p * 3 + 1] + R[i * 3 + 2] * vp[p * 3 + 2] + t[i];
    }

    #pragma unroll
    for (int g = 0; g < 7; ++g)
        Q4[((size_t)h * 7 + g) * S + s] = make_float4(qv[g * 4], qv[g * 4 + 1], qv[g * 4 + 2], qv[g * 4 + 3]);
    #pragma unroll
    for (int g = 0; g < 7; ++g)
        K4[((size_t)h * 7 + g) * S + s] = make_float4(kv[g * 4], kv[g * 4 + 1], kv[g * 4 + 2], kv[g * 4 + 3]);
    #pragma unroll
    for (int g = 0; g < 10; ++g)
        V4[((size_t)h * 10 + g) * S + s] = make_float4(vv[g * 4], vv[g * 4 + 1], vv[g * 4 + 2], vv[g * 4 + 3]);
}

// ---------------------------------------------------------------------------
// Attention (measured-good R6/R10 version, unchanged): one wave per (h, i);
// direct coalesced float4 loads from L2-resident d-major K/V; two-pass
// softmax in-register; butterfly reduces; LDS stage only for the epilogue.
// ---------------------------------------------------------------------------
__global__ __launch_bounds__(256)
void ipa_attn(const float4* __restrict__ Q4, const float4* __restrict__ K4,
              const float4* __restrict__ V4, const float* __restrict__ kb,
              const int* __restrict__ valid,
              const float* __restrict__ rot, const float* __restrict__ trans,
              float* __restrict__ combined)
{
    __shared__ float4 sh[4][10];
    const int h = blockIdx.x;
    const int wave = threadIdx.x >> 6;
    const int lane = threadIdx.x & 63;
    const int i = blockIdx.y * 4 + wave;

    // broadcast-load fused query (7 float4)
    float q[DQK];
    #pragma unroll
    for (int g = 0; g < 7; ++g) {
        float4 v = Q4[((size_t)h * 7 + g) * S + i];
        q[g * 4] = v.x; q[g * 4 + 1] = v.y; q[g * 4 + 2] = v.z; q[g * 4 + 3] = v.w;
    }

    const float* kbh = kb + (size_t)h * S;

    float logit[8];
    float mx = -3.0e38f;
    #pragma unroll
    for (int t = 0; t < 8; ++t) {
        int j = t * 64 + lane;
        float dot = kbh[j];
        #pragma unroll
        for (int g = 0; g < 7; ++g) {
            float4 k = K4[((size_t)h * 7 + g) * S + j];
            dot += q[g * 4] * k.x + q[g * 4 + 1] * k.y + q[g * 4 + 2] * k.z + q[g * 4 + 3] * k.w;
        }
        logit[t] = valid[j] ? dot : NEG_LOGIT;
        mx = fmaxf(mx, logit[t]);
    }
    #pragma unroll
    for (int off = 32; off >= 1; off >>= 1)
        mx = fmaxf(mx, __shfl_xor(mx, off, 64));

    float sum = 0.0f;
    #pragma unroll
    for (int t = 0; t < 8; ++t) {
        logit[t] = __expf(logit[t] - mx);
        sum += logit[t];
    }
    #pragma unroll
    for (int off = 32; off >= 1; off >>= 1)
        sum += __shfl_xor(sum, off, 64);
    const float inv = 1.0f / sum;

    // PV accumulate (unnormalized)
    float4 acc[10];
    #pragma unroll
    for (int g = 0; g < 10; ++g) acc[g] = make_float4(0.f, 0.f, 0.f, 0.f);
    #pragma unroll
    for (int t = 0; t < 8; ++t) {
        int j = t * 64 + lane;
        float p = logit[t];
        #pragma unroll
        for (int g = 0; g < 10; ++g) {
            float4 v = V4[((size_t)h * 10 + g) * S + j];
            acc[g].x += p * v.x; acc[g].y += p * v.y;
            acc[g].z += p * v.z; acc[g].w += p * v.w;
        }
    }
    #pragma unroll
    for (int g = 0; g < 10; ++g) {
        #pragma unroll
        for (int off = 32; off >= 1; off >>= 1) {
            acc[g].x += __shfl_xor(acc[g].x, off, 64);
            acc[g].y += __shfl_xor(acc[g].y, off, 64);
            acc[g].z += __shfl_xor(acc[g].z, off, 64);
            acc[g].w += __shfl_xor(acc[g].w, off, 64);
        }
    }

    // stage to LDS with static indices; read back with dynamic (LDS ok)
    if (lane == 0) {
        #pragma unroll
        for (int g = 0; g < 10; ++g) sh[wave][g] = acc[g];
    }
    const float* shf = (const float*)sh[wave];

    float* crow = combined + (size_t)i * 576;
    if (lane < 16)
        crow[h * 16 + lane] = shf[lane] * inv;

    if (lane < 8) {
        float R[9], t_[3];
        #pragma unroll
        for (int a = 0; a < 9; ++a) R[a] = rot[i * 9 + a];
        #pragma unroll
        for (int a = 0; a < 3; ++a) t_[a] = trans[i * 3 + a];
        int p = lane;
        float d0 = shf[16 + p * 3 + 0] * inv - t_[0];
        float d1 = shf[16 + p * 3 + 1] * inv - t_[1];
        float d2 = shf[16 + p * 3 + 2] * inv - t_[2];
        float pol0 = R[0] * d0 + R[3] * d1 + R[6] * d2;
        float pol1 = R[1] * d0 + R[4] * d1 + R[7] * d2;
        float pol2 = R[2] * d0 + R[5] * d1 + R[8] * d2;
        crow[192 + h * 24 + p * 3 + 0] = pol0;
        crow[192 + h * 24 + p * 3 + 1] = pol1;
        crow[192 + h * 24 + p * 3 + 2] = pol2;
        crow[480 + h * 8 + p] = sqrtf(pol0 * pol0 + pol1 * pol1 + pol2 * pol2);
    }
}

// ---------------------------------------------------------------------------
extern "C" void kernel_launch(void* const* d_in, const int* in_sizes, int n_in,
                              void* d_out, int out_size, void* d_ws, size_t ws_size,
                              hipStream_t stream)
{
    const float* single = (const float*)d_in[0];
    const float* rot    = (const float*)d_in[1];
    const float* trans  = (const float*)d_in[2];
    const float* Wq_s   = (const float*)d_in[3];
    const float* bq_s   = (const float*)d_in[4];
    const float* Wk_s   = (const float*)d_in[5];
    const float* bk_s   = (const float*)d_in[6];
    const float* Wv_s   = (const float*)d_in[7];
    const float* bv_s   = (const float*)d_in[8];
    const float* Wq_p   = (const float*)d_in[9];
    const float* bq_p   = (const float*)d_in[10];
    const float* Wk_p   = (const float*)d_in[11];
    const float* bk_p   = (const float*)d_in[12];
    const float* Wv_p   = (const float*)d_in[13];
    const float* bv_p   = (const float*)d_in[14];
    const float* pw     = (const float*)d_in[15];
    const float* Wo     = (const float*)d_in[16];
    const float* bo     = (const float*)d_in[17];
    const int*   valid  = (const int*)d_in[18];

    float* ws = (float*)d_ws;
    float* X01      = ws;                                  // 2 x 512*1152 (split-K slices)
    float* Q4f      = X01 + (size_t)2 * S * XCOLS;         // 12*7*512*4
    float* K4f      = Q4f + (size_t)H * 7 * S * 4;
    float* V4f      = K4f + (size_t)H * 7 * S * 4;         // 12*10*512*4
    float* kbb      = V4f + (size_t)H * 10 * S * 4;        // 12*512
    float* combined = kbb + (size_t)H * S;                 // 512*576

    dim3 blk(256);

    // 1. split-K projection GEMM with on-the-fly weight gather (512x1152x384)
    gemm_proj<<<dim3(XCOLS / 64, S / 64, 2), blk, 0, stream>>>(
        single, Wq_s, bq_s, Wk_s, bk_s, Wv_s, bv_s,
        Wq_p, bq_p, Wk_p, bk_p, Wv_p, bv_p, X01);

    // 2. fused Q/K/V build (sums X0+X1, rotations applied, d-major float4)
    ipa_points<<<dim3(S * H / 256), blk, 0, stream>>>(X01, rot, trans, pw,
                                                      (float4*)Q4f, (float4*)K4f, (float4*)V4f, kbb);

    // 3. attention -> combined (direct-load two-pass, measured-good)
    ipa_attn<<<dim3(H, S / 4), blk, 0, stream>>>((const float4*)Q4f, (const float4*)K4f,
                                                 (const float4*)V4f, kbb, valid, rot, trans, combined);

    // 4. output projection with query-row masking (BK=48)
    gemm_out<<<dim3(C / 32, S / 32), blk, 0, stream>>>(combined, 576, Wo, C, bo, (float*)d_out, C, 576, valid);
}